// Round 1
// baseline (182.129 us; speedup 1.0000x reference)
//
#include <hip/hip_runtime.h>

#define N_NODES 32768
#define N_EDGES 65536

typedef _Float16 f16;
typedef _Float16 f16x8 __attribute__((ext_vector_type(8)));
typedef float f32x16 __attribute__((ext_vector_type(16)));

// ---------------- ws layout ----------------
// [0, 8388608)            agg   float[N*64]
// [8388608, 8519680)      deg   float[N]
// [8519680, 9109504)      w2swz f16, 9 chunks x 65536 B (swizzled)
// [9109504, 9117696)      w1swz f16, 8192 B (swizzled)
#define WS_AGG   0
#define WS_DEG   8388608
#define WS_W2    8519680
#define WS_W1    9109504

// ============ prep: convert W2 (+b2 row) and W1 to f16 swizzled layouts, degree histogram ============
__global__ __launch_bounds__(256) void k_prep(const float* __restrict__ W1,
                                              const float* __restrict__ W2,
                                              const float* __restrict__ b2,
                                              const int* __restrict__ eidx,
                                              float* __restrict__ deg,
                                              char* __restrict__ w2swz,
                                              char* __restrict__ w1swz) {
  int t = blockIdx.x * 256 + threadIdx.x;
  if (t < 294912) {              // 72 j-rows x 64 h x 64 k
    int j = t >> 12;             // 0..71
    int r = t & 4095;
    int hh = r >> 6;
    int c  = r & 63;
    float v = 0.f;
    if (j < 64)       v = W2[j * 4096 + hh * 64 + c];
    else if (j == 64) v = b2[hh * 64 + c];
    int jc = j >> 3, jl = j & 7;
    int jhl = jl * 64 + hh;
    int byte = jc * 65536 + c * 1024 + ((jhl * 2) ^ ((c & 31) << 4));
    *(f16*)(w2swz + byte) = (f16)v;
  } else if (t < 299008) {       // W1 transpose: 64x64
    int u = t - 294912;
    int j = u & 63, i = u >> 6;
    int byte = j * 128 + ((i * 2) ^ ((j & 7) << 4));
    *(f16*)(w1swz + byte) = (f16)W1[i * 64 + j];
  } else if (t < 364544) {       // degree histogram
    int e = t - 299008;
    int d = eidx[N_EDGES + e];
    unsafeAtomicAdd(&deg[d], 1.0f);
  }
}

// ============ main: h = relu(ee@W1+b1) via MFMA; msg = (h (x) x) @ W2v via MFMA; atomic scatter ============
__global__ __launch_bounds__(256, 1) void k_main(const float* __restrict__ node,
                                                 const float* __restrict__ edge,
                                                 const float* __restrict__ b1,
                                                 const int* __restrict__ eidx,
                                                 const char* __restrict__ w2swz,
                                                 const char* __restrict__ w1swz,
                                                 float* __restrict__ agg) {
  extern __shared__ char smem[];
  char* ldsW2 = smem;            // 65536 B (W1T staged here first: 8192 B)
  char* ldsH  = smem + 65536;    // 8 tiles * 32 rows * 152 B = 38912 B

  const int tid  = threadIdx.x;
  const int lane = tid & 63;
  const int wv   = tid >> 6;     // wave 0..3
  const int ln31 = lane & 31;
  const int half = lane >> 5;
  const int ebase = blockIdx.x * 256;

  // ---- stage W1T (8 KB) ----
  {
    const uint4* src = (const uint4*)w1swz;
    uint4* dst = (uint4*)ldsW2;
    #pragma unroll
    for (int i = 0; i < 2; ++i) dst[tid + i * 256] = src[tid + i * 256];
  }
  __syncthreads();

  // ---- h = relu(ee @ W1 + b1) via MFMA, 2 tiles of 32 edges per wave ----
  const float b1a = b1[ln31];
  const float b1b = b1[32 + ln31];
  for (int tt = 0; tt < 2; ++tt) {
    const int tile = wv * 2 + tt;
    const int e = ebase + tile * 32 + ln31;
    f16x8 a[4];
    const float* er = edge + (long)e * 64 + half * 8;
    #pragma unroll
    for (int kk = 0; kk < 4; ++kk) {
      const float* p = er + kk * 16;
      #pragma unroll
      for (int u = 0; u < 8; ++u) a[kk][u] = (f16)p[u];
    }
    f32x16 c0 = {};
    f32x16 c1 = {};
    #pragma unroll
    for (int kk = 0; kk < 4; ++kk) {
      const int i2 = (kk * 16 + half * 8) * 2;
      f16x8 bv0 = *(const f16x8*)(ldsW2 + ln31 * 128        + (i2 ^ ((ln31 & 7) << 4)));
      f16x8 bv1 = *(const f16x8*)(ldsW2 + (32 + ln31) * 128 + (i2 ^ ((ln31 & 7) << 4)));
      c0 = __builtin_amdgcn_mfma_f32_32x32x16_f16(a[kk], bv0, c0, 0, 0, 0);
      c1 = __builtin_amdgcn_mfma_f32_32x32x16_f16(a[kk], bv1, c1, 0, 0, 0);
    }
    char* hb = ldsH + tile * 4864;
    #pragma unroll
    for (int r = 0; r < 16; ++r) {
      const int m = (r & 3) + 8 * (r >> 2) + 4 * half;
      *(f16*)(hb + m * 152 + ln31 * 2)        = (f16)fmaxf(c0[r] + b1a, 0.f);
      *(f16*)(hb + m * 152 + (32 + ln31) * 2) = (f16)fmaxf(c1[r] + b1b, 0.f);
    }
    if (half == 0) {   // pad rows j=64 (bias row, h=1) and 65..71 (zero)
      #pragma unroll
      for (int jj = 0; jj < 8; ++jj)
        *(f16*)(hb + ln31 * 152 + (64 + jj) * 2) = (f16)(jj == 0 ? 1.f : 0.f);
    }
  }

  // ---- gather x = node_emb[src] into f16 fragments ----
  f16x8 xf[2][4];
  #pragma unroll
  for (int tt = 0; tt < 2; ++tt) {
    const int tile = wv * 2 + tt;
    const int e = ebase + tile * 32 + ln31;
    const int s = eidx[e];
    const float* xr = node + (long)s * 64 + half * 8;
    #pragma unroll
    for (int kk = 0; kk < 4; ++kk) {
      const float* p = xr + kk * 16;
      #pragma unroll
      for (int u = 0; u < 8; ++u) xf[tt][kk][u] = (f16)p[u];
    }
  }

  f32x16 acc[2][2] = {};

  // ---- K loop: 9 chunks x 8 j-rows ----
  const int swz = ln31 << 4;
  for (int jc = 0; jc < 9; ++jc) {
    __syncthreads();
    {
      const uint4* src = (const uint4*)w2swz + jc * 4096;
      uint4* dst = (uint4*)ldsW2;
      #pragma unroll
      for (int i = 0; i < 16; ++i) dst[tid + i * 256] = src[tid + i * 256];
    }
    __syncthreads();
    for (int j = 0; j < 8; ++j) {
      const int jg2 = (jc * 8 + j) * 2;
      const f16 hv0 = *(const f16*)(ldsH + (wv * 2 + 0) * 4864 + ln31 * 152 + jg2);
      const f16 hv1 = *(const f16*)(ldsH + (wv * 2 + 1) * 4864 + ln31 * 152 + jg2);
      f16x8 h0, h1;
      #pragma unroll
      for (int u = 0; u < 8; ++u) { h0[u] = hv0; h1[u] = hv1; }
      #pragma unroll
      for (int kk = 0; kk < 4; ++kk) {
        const int jhl2 = (j * 64 + kk * 16 + half * 8) * 2;
        f16x8 a0 = xf[0][kk] * h0;
        f16x8 a1 = xf[1][kk] * h1;
        f16x8 bv0 = *(const f16x8*)(ldsW2 + ln31 * 1024        + (jhl2 ^ swz));
        f16x8 bv1 = *(const f16x8*)(ldsW2 + (32 + ln31) * 1024 + (jhl2 ^ swz));
        acc[0][0] = __builtin_amdgcn_mfma_f32_32x32x16_f16(a0, bv0, acc[0][0], 0, 0, 0);
        acc[0][1] = __builtin_amdgcn_mfma_f32_32x32x16_f16(a0, bv1, acc[0][1], 0, 0, 0);
        acc[1][0] = __builtin_amdgcn_mfma_f32_32x32x16_f16(a1, bv0, acc[1][0], 0, 0, 0);
        acc[1][1] = __builtin_amdgcn_mfma_f32_32x32x16_f16(a1, bv1, acc[1][1], 0, 0, 0);
      }
    }
  }

  // ---- scatter-add msg into agg[dst] ----
  #pragma unroll
  for (int tt = 0; tt < 2; ++tt) {
    const int ebt = ebase + (wv * 2 + tt) * 32;
    #pragma unroll
    for (int r = 0; r < 16; ++r) {
      const int m = (r & 3) + 8 * (r >> 2) + 4 * half;
      const int d = eidx[N_EDGES + ebt + m];
      unsafeAtomicAdd(&agg[(long)d * 64 + ln31],      acc[tt][0][r]);
      unsafeAtomicAdd(&agg[(long)d * 64 + 32 + ln31], acc[tt][1][r]);
    }
  }
}

// ============ node epilogue: mean-agg + root transform + residual + LayerNorm ============
__global__ __launch_bounds__(256) void k_node(const float* __restrict__ node,
                                              const float* __restrict__ agg,
                                              const float* __restrict__ deg,
                                              const float* __restrict__ root,
                                              const float* __restrict__ bias,
                                              const float* __restrict__ gamma,
                                              const float* __restrict__ beta,
                                              float* __restrict__ out) {
  const int lane = threadIdx.x & 63;
  const int gw = blockIdx.x * 4 + (threadIdx.x >> 6);   // 0..2047
  float r[64];
  #pragma unroll
  for (int h = 0; h < 64; ++h) r[h] = root[h * 64 + lane];
  const float bi = bias[lane], ga = gamma[lane], be = beta[lane];
  for (int n = gw; n < N_NODES; n += 2048) {
    const float x  = node[(long)n * 64 + lane];
    const float a  = agg[(long)n * 64 + lane];
    const float dg = deg[n];
    float pre = a / fmaxf(dg, 1.f) + bi + x;
    float dot = 0.f;
    #pragma unroll
    for (int h = 0; h < 64; ++h) {
      float xh = __int_as_float(__builtin_amdgcn_readlane(__float_as_int(x), h));
      dot = fmaf(xh, r[h], dot);
    }
    pre += dot;
    float s = pre, s2 = pre * pre;
    #pragma unroll
    for (int m = 32; m >= 1; m >>= 1) {
      s  += __shfl_xor(s, m, 64);
      s2 += __shfl_xor(s2, m, 64);
    }
    const float mu  = s * (1.f / 64.f);
    const float var = s2 * (1.f / 64.f) - mu * mu;
    const float inv = rsqrtf(var + 1e-5f);
    out[(long)n * 64 + lane] = (pre - mu) * inv * ga + be;
  }
}

extern "C" void kernel_launch(void* const* d_in, const int* in_sizes, int n_in,
                              void* d_out, int out_size, void* d_ws, size_t ws_size,
                              hipStream_t stream) {
  const float* node  = (const float*)d_in[0];
  const float* edgee = (const float*)d_in[1];
  const float* W1    = (const float*)d_in[2];
  const float* b1    = (const float*)d_in[3];
  const float* W2    = (const float*)d_in[4];
  const float* b2    = (const float*)d_in[5];
  const float* root  = (const float*)d_in[6];
  const float* bias  = (const float*)d_in[7];
  const float* gamma = (const float*)d_in[8];
  const float* beta  = (const float*)d_in[9];
  const int*   eidx  = (const int*)d_in[10];
  float* out = (float*)d_out;

  char* ws = (char*)d_ws;
  float* agg   = (float*)(ws + WS_AGG);
  float* deg   = (float*)(ws + WS_DEG);
  char*  w2swz = ws + WS_W2;
  char*  w1swz = ws + WS_W1;

  // zero agg + deg
  hipMemsetAsync(ws, 0, 8519680, stream);

  k_prep<<<1424, 256, 0, stream>>>(W1, W2, b2, eidx, deg, w2swz, w1swz);

  hipFuncSetAttribute((const void*)k_main, hipFuncAttributeMaxDynamicSharedMemorySize, 104448);
  k_main<<<256, 256, 104448, stream>>>(node, edgee, b1, eidx, w2swz, w1swz, agg);

  k_node<<<512, 256, 0, stream>>>(node, agg, deg, root, bias, gamma, beta, out);
}

// Round 2
// 149.283 us; speedup vs baseline: 1.2200x; 1.2200x over previous
//
#include <hip/hip_runtime.h>

#define N_NODES 32768
#define N_EDGES 65536

typedef _Float16 f16;
typedef _Float16 f16x8 __attribute__((ext_vector_type(8)));
typedef float f32x16 __attribute__((ext_vector_type(16)));

// ---------------- ws layout ----------------
// [0, 8388608)            agg    float[N*64]
// [8388608, 8519680)      deg    float[N]
// [8519680, 9109504)      w2v2   f16, 576 octets x 1024 B (K-octet-major frag layout)
// [9109504, 9117696)      w1v2   f16, 8 octets x 1024 B
// [9117696, 9125888)      rootv2 f16, 8 octets x 1024 B
#define WS_AGG   0
#define WS_DEG   8388608
#define WS_W2    8519680
#define WS_W1    9109504
#define WS_ROOT  9117696

__device__ inline f16 u16_as_f16(unsigned short u) {
  union { unsigned short s; f16 h; } v; v.s = u; return v.h;
}
__device__ inline f16x8 splat8(f16 x) {
  f16x8 r;
  #pragma unroll
  for (int u = 0; u < 8; ++u) r[u] = x;
  return r;
}
__device__ inline f16x8 cvt8(float4 p0, float4 p1) {
  f16x8 a;
  a[0] = (f16)p0.x; a[1] = (f16)p0.y; a[2] = (f16)p0.z; a[3] = (f16)p0.w;
  a[4] = (f16)p1.x; a[5] = (f16)p1.y; a[6] = (f16)p1.z; a[7] = (f16)p1.w;
  return a;
}

// ============ prep: W2(+b2 row), W1, root into f16 MFMA-fragment layouts; degree histogram ============
// layout: octet index oct = row*8 + (h>>4)*2 + ((h>>3)&1); byte = oct*1024 + col*16 + (h&7)*2
__global__ __launch_bounds__(256) void k_prep(const float* __restrict__ W1,
                                              const float* __restrict__ W2,
                                              const float* __restrict__ b2,
                                              const float* __restrict__ root,
                                              const int* __restrict__ eidx,
                                              float* __restrict__ deg,
                                              char* __restrict__ w2v2,
                                              char* __restrict__ w1v2,
                                              char* __restrict__ rootv2) {
  int t = blockIdx.x * 256 + threadIdx.x;
  if (t < 294912) {                       // 72 j-rows x 64 h x 64 col
    int col = t & 63, h = (t >> 6) & 63, j = t >> 12;
    float v = 0.f;
    if (j < 64)       v = W2[j * 4096 + h * 64 + col];
    else if (j == 64) v = b2[h * 64 + col];
    int oct = j * 8 + (h >> 4) * 2 + ((h >> 3) & 1);
    *(f16*)(w2v2 + oct * 1024 + col * 16 + (h & 7) * 2) = (f16)v;
  } else if (t < 299008) {                // W1: 64 i x 64 col
    int u2 = t - 294912; int col = u2 & 63, i = u2 >> 6;
    int oct = (i >> 4) * 2 + ((i >> 3) & 1);
    *(f16*)(w1v2 + oct * 1024 + col * 16 + (i & 7) * 2) = (f16)W1[i * 64 + col];
  } else if (t < 303104) {                // root
    int u2 = t - 299008; int col = u2 & 63, i = u2 >> 6;
    int oct = (i >> 4) * 2 + ((i >> 3) & 1);
    *(f16*)(rootv2 + oct * 1024 + col * 16 + (i & 7) * 2) = (f16)root[i * 64 + col];
  } else if (t < 368640) {                // degree histogram
    int e = t - 303104;
    unsafeAtomicAdd(&deg[eidx[N_EDGES + e]], 1.0f);
  }
}

// ============ main: 512 thr (8 waves), 256 edges/block; col-split waves; dbuf W2 chunks ============
__global__ __launch_bounds__(512, 2) void k_main(const float* __restrict__ node,
                                                 const float* __restrict__ edge,
                                                 const float* __restrict__ b1,
                                                 const int* __restrict__ eidx,
                                                 const char* __restrict__ w2v2,
                                                 const char* __restrict__ w1v2,
                                                 float* __restrict__ agg) {
  extern __shared__ char smem[];          // [0,65536) W2 dbuf; [65536,104448) ldsH
  char* ldsH = smem + 65536;              // 8 tiles x 32 edges x 152 B (72 j f16 + pad)

  const int tid = threadIdx.x;
  const int lane = tid & 63;
  const int wv = tid >> 6;                // 0..7
  const int ln31 = lane & 31;
  const int half = lane >> 5;
  const int ebase = blockIdx.x * 256;

  // ---- phase 1: wave wv computes h = relu(ee@W1+b1) for tile wv (32 edges) ----
  {
    const int e = ebase + wv * 32 + ln31;
    const float4* er = (const float4*)edge + (long)e * 16;
    f32x16 c0 = {}, c1 = {};
    #pragma unroll
    for (int kk = 0; kk < 4; ++kk) {
      f16x8 a = cvt8(er[kk * 4 + half * 2], er[kk * 4 + half * 2 + 1]);
      f16x8 bf0 = *(const f16x8*)(w1v2 + (kk * 2 + half) * 1024 + ln31 * 16);
      f16x8 bf1 = *(const f16x8*)(w1v2 + (kk * 2 + half) * 1024 + 512 + ln31 * 16);
      c0 = __builtin_amdgcn_mfma_f32_32x32x16_f16(a, bf0, c0, 0, 0, 0);
      c1 = __builtin_amdgcn_mfma_f32_32x32x16_f16(a, bf1, c1, 0, 0, 0);
    }
    const float bb0 = b1[ln31], bb1 = b1[32 + ln31];
    char* hb = ldsH + wv * 4864;
    #pragma unroll
    for (int r = 0; r < 16; ++r) {
      const int m = (r & 3) + 8 * (r >> 2) + 4 * half;
      *(f16*)(hb + m * 152 + ln31 * 2)      = (f16)fmaxf(c0[r] + bb0, 0.f);
      *(f16*)(hb + m * 152 + 64 + ln31 * 2) = (f16)fmaxf(c1[r] + bb1, 0.f);
    }
    if (half == 0) {                      // pad j=64 (bias row -> 1.0), j=65..71 -> 0
      *(uint2*)(hb + ln31 * 152 + 128) = make_uint2(0x00003C00u, 0u);
      *(uint2*)(hb + ln31 * 152 + 136) = make_uint2(0u, 0u);
    }
  }

  // ---- gather x = node_emb[src] fragments for this wave's 2 tiles ----
  const int g = wv >> 1;                  // tile-group 0..3 -> tiles 2g, 2g+1
  const int ch = wv & 1;                  // output col half
  f16x8 xf[2][4];
  #pragma unroll
  for (int t = 0; t < 2; ++t) {
    const int e = ebase + (2 * g + t) * 32 + ln31;
    const int s = eidx[e];
    const float4* xr = (const float4*)node + (long)s * 16;
    #pragma unroll
    for (int kk = 0; kk < 4; ++kk)
      xf[t][kk] = cvt8(xr[kk * 4 + half * 2], xr[kk * 4 + half * 2 + 1]);
  }

  // ---- prefetch chunk 0 (reg-staged) ----
  const uint4* w2p = (const uint4*)w2v2;
  uint4 st0 = w2p[tid], st1 = w2p[512 + tid], st2 = w2p[1024 + tid], st3 = w2p[1536 + tid];

  f32x16 accA = {}, accB = {};
  const char* hA = ldsH + (2 * g) * 4864 + ln31 * 152;
  const char* hB = ldsH + (2 * g + 1) * 4864 + ln31 * 152;

  __syncthreads();                        // ldsH ready

  // ---- K loop: 17 chunks x 4 j-rows (j 0..67; 68..71 all-zero, skipped) ----
  for (int c = 0; c < 17; ++c) {
    char* buf = smem + (c & 1) * 32768;
    *(uint4*)(buf + tid * 16)         = st0;
    *(uint4*)(buf + 8192 + tid * 16)  = st1;
    *(uint4*)(buf + 16384 + tid * 16) = st2;
    *(uint4*)(buf + 24576 + tid * 16) = st3;
    if (c < 16) {                         // issue next-chunk loads early (hide under compute)
      const uint4* src = w2p + (c + 1) * 2048;
      st0 = src[tid]; st1 = src[512 + tid]; st2 = src[1024 + tid]; st3 = src[1536 + tid];
    }
    __syncthreads();                      // buf[c&1] ready; also protects c+1 overwrite
    const uint2 hAv = *(const uint2*)(hA + c * 8);
    const uint2 hBv = *(const uint2*)(hB + c * 8);
    #pragma unroll
    for (int j = 0; j < 4; ++j) {
      const unsigned short ua = (unsigned short)((j < 2 ? (hAv.x >> (j * 16)) : (hAv.y >> ((j - 2) * 16))) & 0xffffu);
      const unsigned short ub = (unsigned short)((j < 2 ? (hBv.x >> (j * 16)) : (hBv.y >> ((j - 2) * 16))) & 0xffffu);
      const f16x8 haS = splat8(u16_as_f16(ua));
      const f16x8 hbS = splat8(u16_as_f16(ub));
      #pragma unroll
      for (int kk = 0; kk < 4; ++kk) {
        const f16x8 bf = *(const f16x8*)(buf + (j * 8 + kk * 2 + half) * 1024 + ch * 512 + ln31 * 16);
        accA = __builtin_amdgcn_mfma_f32_32x32x16_f16(xf[0][kk] * haS, bf, accA, 0, 0, 0);
        accB = __builtin_amdgcn_mfma_f32_32x32x16_f16(xf[1][kk] * hbS, bf, accB, 0, 0, 0);
      }
    }
  }

  // ---- scatter-add partial msg ----
  #pragma unroll
  for (int t = 0; t < 2; ++t) {
    const int base = ebase + (2 * g + t) * 32;
    #pragma unroll
    for (int r = 0; r < 16; ++r) {
      const int m = (r & 3) + 8 * (r >> 2) + 4 * half;
      const int d = eidx[N_EDGES + base + m];
      const float v = (t == 0) ? accA[r] : accB[r];
      unsafeAtomicAdd(&agg[(long)d * 64 + ch * 32 + ln31], v);
    }
  }
}

// ============ node epilogue: MFMA root transform + mean-agg + residual + LayerNorm ============
__global__ __launch_bounds__(256) void k_node(const float* __restrict__ node,
                                              const float* __restrict__ agg,
                                              const float* __restrict__ deg,
                                              const char* __restrict__ rootv2,
                                              const float* __restrict__ bias,
                                              const float* __restrict__ gamma,
                                              const float* __restrict__ beta,
                                              float* __restrict__ out) {
  const int tid = threadIdx.x;
  const int lane = tid & 63;
  const int wv = tid >> 6;
  const int ln31 = lane & 31;
  const int half = lane >> 5;
  const int nb = blockIdx.x * 128 + wv * 32;

  f32x16 c0 = {}, c1 = {};
  const float4* xr = (const float4*)node + (long)(nb + ln31) * 16;
  #pragma unroll
  for (int kk = 0; kk < 4; ++kk) {
    f16x8 a = cvt8(xr[kk * 4 + half * 2], xr[kk * 4 + half * 2 + 1]);
    f16x8 b0 = *(const f16x8*)(rootv2 + (kk * 2 + half) * 1024 + ln31 * 16);
    f16x8 b1f = *(const f16x8*)(rootv2 + (kk * 2 + half) * 1024 + 512 + ln31 * 16);
    c0 = __builtin_amdgcn_mfma_f32_32x32x16_f16(a, b0, c0, 0, 0, 0);
    c1 = __builtin_amdgcn_mfma_f32_32x32x16_f16(a, b1f, c1, 0, 0, 0);
  }
  const float bi0 = bias[ln31],  bi1 = bias[32 + ln31];
  const float g0  = gamma[ln31], g1  = gamma[32 + ln31];
  const float be0 = beta[ln31],  be1 = beta[32 + ln31];
  #pragma unroll
  for (int r = 0; r < 16; ++r) {
    const int m = (r & 3) + 8 * (r >> 2) + 4 * half;
    const int n = nb + m;
    const float rd = 1.f / fmaxf(deg[n], 1.f);
    const float pre0 = agg[n * 64 + ln31] * rd + c0[r] + bi0 + node[n * 64 + ln31];
    const float pre1 = agg[n * 64 + 32 + ln31] * rd + c1[r] + bi1 + node[n * 64 + 32 + ln31];
    float s = pre0 + pre1, s2 = pre0 * pre0 + pre1 * pre1;
    #pragma unroll
    for (int mk = 16; mk >= 1; mk >>= 1) {
      s  += __shfl_xor(s, mk, 64);
      s2 += __shfl_xor(s2, mk, 64);
    }
    const float mu  = s * 0.015625f;
    const float var = s2 * 0.015625f - mu * mu;
    const float inv = rsqrtf(var + 1e-5f);
    out[n * 64 + ln31]      = (pre0 - mu) * inv * g0 + be0;
    out[n * 64 + 32 + ln31] = (pre1 - mu) * inv * g1 + be1;
  }
}

extern "C" void kernel_launch(void* const* d_in, const int* in_sizes, int n_in,
                              void* d_out, int out_size, void* d_ws, size_t ws_size,
                              hipStream_t stream) {
  const float* node  = (const float*)d_in[0];
  const float* edgee = (const float*)d_in[1];
  const float* W1    = (const float*)d_in[2];
  const float* b1    = (const float*)d_in[3];
  const float* W2    = (const float*)d_in[4];
  const float* b2    = (const float*)d_in[5];
  const float* root  = (const float*)d_in[6];
  const float* bias  = (const float*)d_in[7];
  const float* gamma = (const float*)d_in[8];
  const float* beta  = (const float*)d_in[9];
  const int*   eidx  = (const int*)d_in[10];
  float* out = (float*)d_out;

  char* ws = (char*)d_ws;
  float* agg    = (float*)(ws + WS_AGG);
  float* deg    = (float*)(ws + WS_DEG);
  char*  w2v2   = ws + WS_W2;
  char*  w1v2   = ws + WS_W1;
  char*  rootv2 = ws + WS_ROOT;

  hipMemsetAsync(ws, 0, 8519680, stream);   // zero agg + deg

  k_prep<<<1440, 256, 0, stream>>>(W1, W2, b2, root, eidx, deg, w2v2, w1v2, rootv2);

  hipFuncSetAttribute((const void*)k_main, hipFuncAttributeMaxDynamicSharedMemorySize, 104448);
  k_main<<<256, 512, 104448, stream>>>(node, edgee, b1, eidx, w2v2, w1v2, agg);

  k_node<<<256, 256, 0, stream>>>(node, agg, deg, rootv2, bias, gamma, beta, out);
}

// Round 3
// 143.437 us; speedup vs baseline: 1.2698x; 1.0408x over previous
//
#include <hip/hip_runtime.h>

#define N_NODES 32768
#define N_EDGES 65536

typedef _Float16 f16;
typedef _Float16 f16x8 __attribute__((ext_vector_type(8)));
typedef float f32x16 __attribute__((ext_vector_type(16)));

// ---------------- ws layout ----------------
// [0, 8388608)            agg     float[N*64]
// [8388608, 8519680)      deg     float[N]
// [8519680, 9060352)      w2v2    f16, 66 j-rows x 8 octets x 1024 B (j 0..63 = W2, 64 = b2, 65 = 0)
// [9060352, 9068544)      w1v2    f16, 8 octets x 1024 B
// [9068544, 9076736)      rootIv2 f16 (root + I), 8 octets x 1024 B
#define WS_AGG   0
#define WS_DEG   8388608
#define WS_W2    8519680
#define WS_W1    9060352
#define WS_ROOT  9068544

#define MFMA(a, b, c) __builtin_amdgcn_mfma_f32_32x32x16_f16((a), (b), (c), 0, 0, 0)

__device__ inline f16 u16_as_f16(unsigned short u) {
  union { unsigned short s; f16 h; } v; v.s = u; return v.h;
}
__device__ inline f16x8 splat8(f16 x) {
  f16x8 r;
  #pragma unroll
  for (int u = 0; u < 8; ++u) r[u] = x;
  return r;
}
__device__ inline f16x8 cvt8(float4 p0, float4 p1) {
  f16x8 a;
  a[0] = (f16)p0.x; a[1] = (f16)p0.y; a[2] = (f16)p0.z; a[3] = (f16)p0.w;
  a[4] = (f16)p1.x; a[5] = (f16)p1.y; a[6] = (f16)p1.z; a[7] = (f16)p1.w;
  return a;
}

// ============ prep (output-indexed, coalesced both sides) ============
// frag layout: oct = j*8 + (h>>4)*2 + ((h>>3)&1); byte = oct*1024 + col*16 + (h&7)*2
__global__ __launch_bounds__(256) void k_prep(const float* __restrict__ W1,
                                              const float* __restrict__ W2,
                                              const float* __restrict__ b2,
                                              const float* __restrict__ root,
                                              const int* __restrict__ eidx,
                                              float* __restrict__ deg,
                                              char* __restrict__ w2v2,
                                              char* __restrict__ w1v2,
                                              char* __restrict__ rootIv2) {
  int t = blockIdx.x * 256 + threadIdx.x;
  if (t < 270336) {                      // w2v2: 66 rows x 4096 halfwords
    int oct = t >> 9, q = t & 511;
    int col = q >> 3, hl = q & 7;
    int j = oct >> 3, sub = oct & 7;
    int h = (sub >> 1) * 16 + (sub & 1) * 8 + hl;
    float v = 0.f;
    if (j < 64)       v = W2[j * 4096 + h * 64 + col];
    else if (j == 64) v = b2[h * 64 + col];
    *(f16*)(w2v2 + t * 2) = (f16)v;
  } else if (t < 274432) {               // w1v2
    int u = t - 270336;
    int oct = u >> 9, q = u & 511, col = q >> 3, hl = q & 7;
    int i = (oct >> 1) * 16 + (oct & 1) * 8 + hl;
    *(f16*)(w1v2 + u * 2) = (f16)W1[i * 64 + col];
  } else if (t < 278528) {               // rootI = root + I
    int u = t - 274432;
    int oct = u >> 9, q = u & 511, col = q >> 3, hl = q & 7;
    int i = (oct >> 1) * 16 + (oct & 1) * 8 + hl;
    float v = root[i * 64 + col] + (i == col ? 1.f : 0.f);
    *(f16*)(rootIv2 + u * 2) = (f16)v;
  } else if (t < 344064) {               // degree histogram
    int e = t - 278528;
    unsafeAtomicAdd(&deg[eidx[N_EDGES + e]], 1.0f);
  }
}

// ============ main: 256 blocks x 256 thr; B direct from global (L2); no K-loop barriers ============
__global__ __launch_bounds__(256, 1) void k_main(const float* __restrict__ node,
                                                 const float* __restrict__ edge,
                                                 const float* __restrict__ b1,
                                                 const int* __restrict__ eidx,
                                                 const char* __restrict__ w2v2,
                                                 const char* __restrict__ w1v2,
                                                 float* __restrict__ agg) {
  __shared__ char ldsH[34816];           // 256 edges x 136 B (64 j-f16 + 8 pad)

  const int tid = threadIdx.x;
  const int lane = tid & 63;
  const int wv = tid >> 6;               // 0..3
  const int ln31 = lane & 31;
  const int half = lane >> 5;
  const int ebase = blockIdx.x * 256;

  // ---- phase 1: wave wv computes h = relu(ee@W1+b1) for tiles 2wv, 2wv+1 ----
  const char* w1p = w1v2 + half * 1024 + ln31 * 16;
  #pragma unroll
  for (int t = 0; t < 2; ++t) {
    const int tile = 2 * wv + t;
    const int e = ebase + tile * 32 + ln31;
    const float4* er = (const float4*)edge + (long)e * 16;
    f32x16 c0 = {}, c1 = {};
    #pragma unroll
    for (int kk = 0; kk < 4; ++kk) {
      f16x8 a = cvt8(er[kk * 4 + half * 2], er[kk * 4 + half * 2 + 1]);
      f16x8 bf0 = *(const f16x8*)(w1p + (kk * 2 << 10));
      f16x8 bf1 = *(const f16x8*)(w1p + (kk * 2 << 10) + 512);
      c0 = MFMA(a, bf0, c0);
      c1 = MFMA(a, bf1, c1);
    }
    const float bb0 = b1[ln31], bb1 = b1[32 + ln31];
    char* hb = ldsH + tile * 32 * 136;
    #pragma unroll
    for (int r = 0; r < 16; ++r) {
      const int m = (r & 3) + 8 * (r >> 2) + 4 * half;
      *(f16*)(hb + m * 136 + ln31 * 2)      = (f16)fmaxf(c0[r] + bb0, 0.f);
      *(f16*)(hb + m * 136 + 64 + ln31 * 2) = (f16)fmaxf(c1[r] + bb1, 0.f);
    }
  }

  const int ch = wv & 1;                 // output col half
  const int g  = wv >> 1;                // edge group: tiles 4g..4g+3

  // ---- gather x = node_emb[src] fragments, 4 tiles ----
  f16x8 xf[4][4];
  #pragma unroll
  for (int t = 0; t < 4; ++t) {
    const int e = ebase + (g * 4 + t) * 32 + ln31;
    const int s = eidx[e];
    const float4* xr = (const float4*)node + (long)s * 16;
    #pragma unroll
    for (int kk = 0; kk < 4; ++kk)
      xf[t][kk] = cvt8(xr[kk * 4 + half * 2], xr[kk * 4 + half * 2 + 1]);
  }

  // ---- prologue: bufA = chunk 0 (j 0,1) ----
  const char* wp = w2v2 + half * 1024 + ch * 512 + ln31 * 16;
  f16x8 bufA[8], bufB[8];
  #pragma unroll
  for (int jj = 0; jj < 2; ++jj)
    #pragma unroll
    for (int kk = 0; kk < 4; ++kk)
      bufA[jj * 4 + kk] = *(const f16x8*)(wp + ((jj * 8 + kk * 2) << 10));

  f32x16 acc[4] = {};
  const char* hp[4];
  #pragma unroll
  for (int t = 0; t < 4; ++t) hp[t] = ldsH + (g * 128 + t * 32 + ln31) * 136;

  __syncthreads();                       // ldsH ready

  // ---- K loop: 16 pairs of 2-j chunks (j 0..63), reg double-buffered B ----
  for (int cp = 0; cp < 16; ++cp) {
    const char* base = wp + (cp << 15);  // j0 = 4*cp
    uint2 hv[4];
    #pragma unroll
    for (int t = 0; t < 4; ++t) hv[t] = *(const uint2*)(hp[t] + cp * 8);

    #pragma unroll
    for (int jj = 0; jj < 2; ++jj)       // load chunk 2cp+1 (j 4cp+2, 4cp+3)
      #pragma unroll
      for (int kk = 0; kk < 4; ++kk)
        bufB[jj * 4 + kk] = *(const f16x8*)(base + 16384 + ((jj * 8 + kk * 2) << 10));

    #pragma unroll
    for (int jj = 0; jj < 2; ++jj) {     // compute chunk 2cp (j 4cp+jj)
      f16x8 sp[4];
      #pragma unroll
      for (int t = 0; t < 4; ++t)
        sp[t] = splat8(u16_as_f16((unsigned short)(hv[t].x >> (jj * 16))));
      #pragma unroll
      for (int kk = 0; kk < 4; ++kk)
        #pragma unroll
        for (int t = 0; t < 4; ++t)
          acc[t] = MFMA(xf[t][kk] * sp[t], bufA[jj * 4 + kk], acc[t]);
    }

    #pragma unroll
    for (int jj = 0; jj < 2; ++jj)       // load next pair's first chunk (cp=15 -> j 64,65: rows exist)
      #pragma unroll
      for (int kk = 0; kk < 4; ++kk)
        bufA[jj * 4 + kk] = *(const f16x8*)(base + 32768 + ((jj * 8 + kk * 2) << 10));

    #pragma unroll
    for (int jj = 0; jj < 2; ++jj) {     // compute chunk 2cp+1 (j 4cp+2+jj)
      f16x8 sp[4];
      #pragma unroll
      for (int t = 0; t < 4; ++t)
        sp[t] = splat8(u16_as_f16((unsigned short)(hv[t].y >> (jj * 16))));
      #pragma unroll
      for (int kk = 0; kk < 4; ++kk)
        #pragma unroll
        for (int t = 0; t < 4; ++t)
          acc[t] = MFMA(xf[t][kk] * sp[t], bufB[jj * 4 + kk], acc[t]);
    }
  }

  // ---- epilogue: j = 64 bias row, A = x (h == 1 exactly) ----
  #pragma unroll
  for (int kk = 0; kk < 4; ++kk)
    #pragma unroll
    for (int t = 0; t < 4; ++t)
      acc[t] = MFMA(xf[t][kk], bufA[kk], acc[t]);

  // ---- scatter-add msg into agg[dst] ----
  #pragma unroll
  for (int t = 0; t < 4; ++t) {
    const int base_e = ebase + (g * 4 + t) * 32;
    #pragma unroll
    for (int r = 0; r < 16; ++r) {
      const int m = (r & 3) + 8 * (r >> 2) + 4 * half;
      const int d = eidx[N_EDGES + base_e + m];
      unsafeAtomicAdd(&agg[(long)d * 64 + ch * 32 + ln31], acc[t][r]);
    }
  }
}

// ============ node epilogue: MFMA (root+I) transform + mean-agg + LayerNorm ============
__global__ __launch_bounds__(256) void k_node(const float* __restrict__ node,
                                              const float* __restrict__ agg,
                                              const float* __restrict__ deg,
                                              const char* __restrict__ rootIv2,
                                              const float* __restrict__ bias,
                                              const float* __restrict__ gamma,
                                              const float* __restrict__ beta,
                                              float* __restrict__ out) {
  const int tid = threadIdx.x;
  const int lane = tid & 63;
  const int wv = tid >> 6;
  const int ln31 = lane & 31;
  const int half = lane >> 5;
  const int nb = blockIdx.x * 128 + wv * 32;

  const char* rp = rootIv2 + half * 1024 + ln31 * 16;
  f32x16 c0 = {}, c1 = {};
  const float4* xr = (const float4*)node + (long)(nb + ln31) * 16;
  #pragma unroll
  for (int kk = 0; kk < 4; ++kk) {
    f16x8 a = cvt8(xr[kk * 4 + half * 2], xr[kk * 4 + half * 2 + 1]);
    f16x8 b0 = *(const f16x8*)(rp + (kk * 2 << 10));
    f16x8 b1f = *(const f16x8*)(rp + (kk * 2 << 10) + 512);
    c0 = MFMA(a, b0, c0);
    c1 = MFMA(a, b1f, c1);
  }
  const float bi0 = bias[ln31],  bi1 = bias[32 + ln31];
  const float g0  = gamma[ln31], g1  = gamma[32 + ln31];
  const float be0 = beta[ln31],  be1 = beta[32 + ln31];
  #pragma unroll
  for (int r = 0; r < 16; ++r) {
    const int m = (r & 3) + 8 * (r >> 2) + 4 * half;
    const int n = nb + m;
    const float rd = 1.f / fmaxf(deg[n], 1.f);
    const float pre0 = agg[n * 64 + ln31] * rd + c0[r] + bi0;
    const float pre1 = agg[n * 64 + 32 + ln31] * rd + c1[r] + bi1;
    float s = pre0 + pre1, s2 = pre0 * pre0 + pre1 * pre1;
    #pragma unroll
    for (int mk = 16; mk >= 1; mk >>= 1) {
      s  += __shfl_xor(s, mk, 64);
      s2 += __shfl_xor(s2, mk, 64);
    }
    const float mu  = s * 0.015625f;
    const float var = s2 * 0.015625f - mu * mu;
    const float inv = rsqrtf(var + 1e-5f);
    out[n * 64 + ln31]      = (pre0 - mu) * inv * g0 + be0;
    out[n * 64 + 32 + ln31] = (pre1 - mu) * inv * g1 + be1;
  }
}

extern "C" void kernel_launch(void* const* d_in, const int* in_sizes, int n_in,
                              void* d_out, int out_size, void* d_ws, size_t ws_size,
                              hipStream_t stream) {
  const float* node  = (const float*)d_in[0];
  const float* edgee = (const float*)d_in[1];
  const float* W1    = (const float*)d_in[2];
  const float* b1    = (const float*)d_in[3];
  const float* W2    = (const float*)d_in[4];
  const float* b2    = (const float*)d_in[5];
  const float* root  = (const float*)d_in[6];
  const float* bias  = (const float*)d_in[7];
  const float* gamma = (const float*)d_in[8];
  const float* beta  = (const float*)d_in[9];
  const int*   eidx  = (const int*)d_in[10];
  float* out = (float*)d_out;

  char* ws = (char*)d_ws;
  float* agg     = (float*)(ws + WS_AGG);
  float* deg     = (float*)(ws + WS_DEG);
  char*  w2v2    = ws + WS_W2;
  char*  w1v2    = ws + WS_W1;
  char*  rootIv2 = ws + WS_ROOT;

  hipMemsetAsync(ws, 0, 8519680, stream);   // zero agg + deg

  k_prep<<<1344, 256, 0, stream>>>(W1, W2, b2, root, eidx, deg, w2v2, w1v2, rootIv2);
  k_main<<<256, 256, 0, stream>>>(node, edgee, b1, eidx, w2v2, w1v2, agg);
  k_node<<<256, 256, 0, stream>>>(node, agg, deg, rootIv2, bias, gamma, beta, out);
}